// Round 13
// baseline (24.290 us; speedup 1.0000x reference)
//
#include <hip/hip_runtime.h>
#include <math.h>

#define BB 512
#define VV 16
#define NN 8192
#define YY 32
#define HID 512
#define TT 8
#define GB 2                  // batches per block (single kernel)
#define NBLK (BB / GB)        // 256 blocks -> 1 per CU
#define NTHR 1024
#define W1N (52 * HID)        // 26624 floats
#define W1PT (W1N / NTHR)     // 26 per thread

__device__ __forceinline__ float gelu_exact(float x) {
    return x * 0.5f * (1.0f + erff(x * 0.70710678118654752440f));
}

// Robust parse of the scalar `t` (int32/int64/f32/f64) — 2 loads, cheap.
__device__ __forceinline__ int parse_t(const unsigned* p) {
    unsigned w0 = p[0];
    if (w0 >= 1u && w0 <= 64u) return (int)w0;
    if (w0 == 0u) {
        unsigned w1 = p[1];
        if (w1 == 0u) return 0;
        double d = __hiloint2double((int)w1, (int)w0);
        if (d >= 0.0 && d <= 64.0 && d == floor(d)) return (int)d;
        return 0;
    }
    float f = __uint_as_float(w0);
    if (f >= 0.0f && f <= 64.0f && f == floorf(f)) return (int)f;
    return TT;
}

__global__ __launch_bounds__(NTHR) void fused_model_kernel(
    const int* __restrict__ tables, const int* __restrict__ sigma,
    const int* __restrict__ base_obs, const int* __restrict__ actions,
    const int* __restrict__ responses, const unsigned* __restrict__ tptr,
    const float* __restrict__ W1, const float* __restrict__ b1,
    const float* __restrict__ W2, const float* __restrict__ b2,
    const float* __restrict__ Wy1, const float* __restrict__ by1,
    const float* __restrict__ Wy2, const float* __restrict__ by2,
    float* __restrict__ out)
{
    const int tid = threadIdx.x;
    const int g   = tid >> 9;          // batch slot within block: 0/1
    const int lt  = tid & 511;         // lane within slot
    const int b   = blockIdx.x * GB + g;

    __shared__ float    s_W1[W1N];           // 104 KB staged copy of W1
    __shared__ int      s_cnt_sig[GB][YY];
    __shared__ unsigned s_labmask[GB][VV];
    __shared__ int      s_count[GB];
    __shared__ float    s_feat[GB][52];
    __shared__ float    s_h[GB][HID];        // h, then hy
    __shared__ float    s_part[GB][HID];
    __shared__ float    s_fy[GB][YY + VV];
    __shared__ float    s_logits[GB][VV];
    __shared__ int      s_act[GB][TT], s_resp[GB][TT];
    __shared__ int      s_t;

    // ---- T14 async-STAGE: issue W1 loads BEFORE the scan (latency hides under it) ----
    float wreg[W1PT];
    #pragma unroll
    for (int j = 0; j < W1PT; ++j) wreg[j] = W1[tid + j * NTHR];   // coalesced, independent

    if (tid < GB * YY) s_cnt_sig[tid >> 5][tid & 31] = 0;
    if (tid < GB * VV) s_labmask[tid >> 4][tid & 15] = 0u;
    if (tid < GB) s_count[tid] = 0;
    if (tid == 0) { int t = parse_t(tptr); s_t = t > TT ? TT : t; }
    if (lt < TT) { s_act[g][lt] = actions[b * TT + lt]; s_resp[g][lt] = responses[b * TT + lt]; }
    __syncthreads();

    const int  base    = base_obs[b];
    const int  t       = s_t;
    const long rowbase = (long)b * VV * NN;

    // ---- phase 1: scan row 0 (16 states/thread via 4x int4); early-exit gathers ----
    {
        const int n0 = lt * 16;
        const int4* tp = (const int4*)(tables + rowbase + n0);
        int4 x0 = tp[0], x1 = tp[1], x2 = tp[2], x3 = tp[3];
        int vals[16] = { x0.x, x0.y, x0.z, x0.w, x1.x, x1.y, x1.z, x1.w,
                         x2.x, x2.y, x2.z, x2.w, x3.x, x3.y, x3.z, x3.w };
        #pragma unroll
        for (int s = 0; s < 16; ++s) {
            if (vals[s] == base) {
                const int n = n0 + s;
                bool ok = true;
                for (int j = 0; j < t; ++j)
                    if (tables[rowbase + s_act[g][j] * NN + n] != s_resp[g][j]) { ok = false; break; }
                if (ok) {
                    atomicAdd(&s_count[g], 1);
                    atomicAdd(&s_cnt_sig[g][sigma[(long)b * NN + n] & 31], 1);
                    #pragma unroll
                    for (int v = 0; v < VV; ++v)
                        atomicOr(&s_labmask[g][v], 1u << (tables[rowbase + v * NN + n] & 31));
                }
            }
        }
    }

    // ---- stage W1 to LDS (weight loads completed during the scan) ----
    #pragma unroll
    for (int j = 0; j < W1PT; ++j) s_W1[tid + j * NTHR] = wreg[j];
    __syncthreads();

    // ---- phase 2: feature build (first wave: lanes 0-31 = slot0, 32-63 = slot1) ----
    if (tid < GB * YY) {
        const int gg = tid >> 5, y = tid & 31;
        int cnt = s_count[gg];
        float inv = 1.0f / (cnt > 0 ? (float)cnt : 1.0f);
        float p = (float)s_cnt_sig[gg][y] * inv;
        s_feat[gg][y] = p;
        // safe entropy: 0*log(0) := 0 (matches grader-np; identical for p>0)
        float et = p > 0.0f ? -p * logf(p) : 0.0f;
        float t1 = p, t2 = -1e30f;
        #pragma unroll
        for (int off = 1; off < 32; off <<= 1) {
            float oe = __shfl_xor(et, off, 32);
            float o1 = __shfl_xor(t1, off, 32);
            float o2 = __shfl_xor(t2, off, 32);
            et += oe;
            float hi = fmaxf(t1, o1);
            float lo = fminf(t1, o1);
            t2 = fmaxf(lo, fmaxf(t2, o2));
            t1 = hi;
        }
        if (y == 0) {
            s_feat[gg][48] = et;
            s_feat[gg][49] = t1;
            s_feat[gg][50] = t2;
            s_feat[gg][51] = cnt > 0 ? inv : 0.0f;   // max(state_dist)
        }
    }
    if (tid < GB * VV) {
        const int gg = tid >> 4, v = tid & 15;
        s_feat[gg][YY + v] = (float)__popc(s_labmask[gg][v]);
    }
    __syncthreads();

    // ---- phase 3: h = gelu(feat @ W1 + b1), W1 from LDS ----
    {
        float acc = b1[lt];
        #pragma unroll
        for (int k = 0; k < 52; ++k) acc += s_feat[g][k] * s_W1[k * HID + lt];
        s_h[g][lt] = gelu_exact(acc);
    }
    __syncthreads();

    // ---- phase 4: z_logits = h @ W2 + b2 (chunked partials, round-10 order) ----
    {
        const int o = lt & 15, kc = lt >> 4;       // 32 chunks of 16
        float acc = 0.0f;
        #pragma unroll
        for (int q = 0; q < 16; ++q) {
            const int k = kc * 16 + q;
            acc += s_h[g][k] * W2[k * VV + o];
        }
        s_part[g][lt] = acc;
    }
    __syncthreads();
    if (tid < GB * VV) {
        const int gg = tid >> 4, o = tid & 15;
        float acc = b2[o];
        for (int kc = 0; kc < 32; ++kc) acc += s_part[gg][kc * 16 + o];
        s_logits[gg][o] = acc;
    }
    __syncthreads();

    // ---- phase 5: softmax + straight-through one-hot (one lane per slot) ----
    if (tid < GB) {
        const int gg = tid;
        float mx = s_logits[gg][0]; int am = 0;    // first-max tiebreak == np.argmax
        for (int o = 1; o < VV; ++o) if (s_logits[gg][o] > mx) { mx = s_logits[gg][o]; am = o; }
        float sum = 0.0f;
        float e[VV];
        #pragma unroll
        for (int o = 0; o < VV; ++o) { e[o] = expf(s_logits[gg][o] - mx); sum += e[o]; }
        float isum = 1.0f / sum;
        #pragma unroll
        for (int o = 0; o < VV; ++o) {
            float soft = e[o] * isum;
            s_fy[gg][YY + o] = ((o == am ? 1.0f : 0.0f) - soft) + soft;  // (hard - sg(soft)) + soft
        }
    }
    if (tid < GB * YY) {
        const int gg = tid >> 5, y = tid & 31;
        s_fy[gg][y] = s_feat[gg][y];
    }
    __syncthreads();

    // ---- phase 6: hy = gelu(fy @ Wy1 + by1) ----
    {
        float acc = by1[lt];
        #pragma unroll
        for (int k = 0; k < 48; ++k) acc += s_fy[g][k] * Wy1[k * HID + lt];
        s_h[g][lt] = gelu_exact(acc);
    }
    __syncthreads();

    // ---- phase 7: out = hy @ Wy2 + by2 (order identical to rounds 10-12) ----
    {
        const int o = lt & 31, kc = lt >> 5;       // 16 chunks of 32
        float acc = 0.0f;
        #pragma unroll
        for (int q = 0; q < 32; ++q) {
            const int k = kc * 32 + q;
            acc += s_h[g][k] * Wy2[k * YY + o];
        }
        s_part[g][lt] = acc;
    }
    __syncthreads();
    if (tid < GB * YY) {
        const int gg = tid >> 5, o = tid & 31;
        float acc = by2[o];
        for (int kc = 0; kc < 16; ++kc) acc += s_part[gg][kc * 32 + o];
        out[(blockIdx.x * GB + gg) * YY + o] = acc;
    }
}

extern "C" void kernel_launch(void* const* d_in, const int* in_sizes, int n_in,
                              void* d_out, int out_size, void* d_ws, size_t ws_size,
                              hipStream_t stream) {
    // Size-based dispatch (unique sizes); {base_obs,b1,by1}=512 and
    // {actions,responses}=4096 resolved by dict order (verified rounds 8-10).
    const void *tables = nullptr, *sigma = nullptr, *tptr = nullptr;
    const void *W1 = nullptr, *W2 = nullptr, *Wy1 = nullptr, *Wy2 = nullptr;
    const void *b2 = nullptr, *by2 = nullptr;
    const void* amb512[3] = { nullptr, nullptr, nullptr }; int n512 = 0;
    const void* amb4096[2] = { nullptr, nullptr };         int n4096 = 0;

    for (int i = 0; i < n_in; ++i) {
        switch (in_sizes[i]) {
            case 67108864: tables = d_in[i]; break;           // 512*16*8192
            case 4194304:  sigma  = d_in[i]; break;           // 512*8192
            case 26624:    W1     = d_in[i]; break;           // 52*512
            case 8192:     W2     = d_in[i]; break;           // 512*16
            case 24576:    Wy1    = d_in[i]; break;           // 48*512
            case 16384:    Wy2    = d_in[i]; break;           // 512*32
            case 16:       b2     = d_in[i]; break;
            case 32:       by2    = d_in[i]; break;
            case 1:        tptr   = d_in[i]; break;
            case 4096:     if (n4096 < 2) amb4096[n4096++] = d_in[i]; break;
            case 512:      if (n512  < 3) amb512[n512++]   = d_in[i]; break;
            default: break;
        }
    }

    const void* base_obs  = amb512[0];
    const void* b1        = amb512[1];
    const void* by1       = amb512[2];
    const void* actions   = amb4096[0];
    const void* responses = amb4096[1];

    fused_model_kernel<<<NBLK, NTHR, 0, stream>>>(
        (const int*)tables, (const int*)sigma,
        (const int*)base_obs, (const int*)actions, (const int*)responses,
        (const unsigned*)tptr,
        (const float*)W1, (const float*)b1,
        (const float*)W2, (const float*)b2,
        (const float*)Wy1, (const float*)by1,
        (const float*)Wy2, (const float*)by2,
        (float*)d_out);
}

// Round 14
// 23.384 us; speedup vs baseline: 1.0387x; 1.0387x over previous
//
#include <hip/hip_runtime.h>
#include <math.h>

#define BB 512
#define VV 16
#define NN 8192
#define YY 32
#define HID 512
#define TT 8
#define GB 2                  // batches per block (single kernel)
#define NBLK (BB / GB)        // 256 blocks -> 1 per CU
#define NTHR 1024

__device__ __forceinline__ float gelu_exact(float x) {
    return x * 0.5f * (1.0f + erff(x * 0.70710678118654752440f));
}

// Robust parse of the scalar `t` (int32/int64/f32/f64) — 2 loads, cheap.
__device__ __forceinline__ int parse_t(const unsigned* p) {
    unsigned w0 = p[0];
    if (w0 >= 1u && w0 <= 64u) return (int)w0;
    if (w0 == 0u) {
        unsigned w1 = p[1];
        if (w1 == 0u) return 0;
        double d = __hiloint2double((int)w1, (int)w0);
        if (d >= 0.0 && d <= 64.0 && d == floor(d)) return (int)d;
        return 0;
    }
    float f = __uint_as_float(w0);
    if (f >= 0.0f && f <= 64.0f && f == floorf(f)) return (int)f;
    return TT;
}

__global__ __launch_bounds__(NTHR) void fused_model_kernel(
    const int* __restrict__ tables, const int* __restrict__ sigma,
    const int* __restrict__ base_obs, const int* __restrict__ actions,
    const int* __restrict__ responses, const unsigned* __restrict__ tptr,
    const float* __restrict__ W1, const float* __restrict__ b1,
    const float* __restrict__ W2, const float* __restrict__ b2,
    const float* __restrict__ Wy1, const float* __restrict__ by1,
    const float* __restrict__ Wy2, const float* __restrict__ by2,
    float* __restrict__ out)
{
    const int tid = threadIdx.x;
    const int g   = tid >> 9;          // batch slot within block: 0/1
    const int lt  = tid & 511;         // lane within slot
    const int b   = blockIdx.x * GB + g;

    __shared__ int      s_cnt_sig[GB][YY];
    __shared__ unsigned s_labmask[GB][VV];
    __shared__ int      s_count[GB];
    __shared__ float    s_feat[GB][52];
    __shared__ float    s_h[GB][HID];        // h, then hy
    __shared__ float    s_part[GB][HID];
    __shared__ float    s_fy[GB][YY + VV];
    __shared__ float    s_logits[GB][VV];
    __shared__ int      s_act[GB][TT], s_resp[GB][TT];
    __shared__ int      s_t;

    if (tid < GB * YY) s_cnt_sig[tid >> 5][tid & 31] = 0;
    if (tid < GB * VV) s_labmask[tid >> 4][tid & 15] = 0u;
    if (tid < GB) s_count[tid] = 0;
    if (tid == 0) { int t = parse_t(tptr); s_t = t > TT ? TT : t; }
    if (lt < TT) { s_act[g][lt] = actions[b * TT + lt]; s_resp[g][lt] = responses[b * TT + lt]; }
    __syncthreads();

    const int  base    = base_obs[b];
    const int  t       = s_t;
    const long rowbase = (long)b * VV * NN;

    // ---- phase 1: scan row 0 (16 states/thread via 4x int4); early-exit gathers ----
    {
        const int n0 = lt * 16;
        const int4* tp = (const int4*)(tables + rowbase + n0);
        int4 x0 = tp[0], x1 = tp[1], x2 = tp[2], x3 = tp[3];
        int vals[16] = { x0.x, x0.y, x0.z, x0.w, x1.x, x1.y, x1.z, x1.w,
                         x2.x, x2.y, x2.z, x2.w, x3.x, x3.y, x3.z, x3.w };
        #pragma unroll
        for (int s = 0; s < 16; ++s) {
            if (vals[s] == base) {
                const int n = n0 + s;
                bool ok = true;
                for (int j = 0; j < t; ++j)
                    if (tables[rowbase + s_act[g][j] * NN + n] != s_resp[g][j]) { ok = false; break; }
                if (ok) {
                    atomicAdd(&s_count[g], 1);
                    atomicAdd(&s_cnt_sig[g][sigma[(long)b * NN + n] & 31], 1);
                    #pragma unroll
                    for (int v = 0; v < VV; ++v)
                        atomicOr(&s_labmask[g][v], 1u << (tables[rowbase + v * NN + n] & 31));
                }
            }
        }
    }
    __syncthreads();

    // ---- phase 2: feature build (first wave: lanes 0-31 = slot0, 32-63 = slot1) ----
    if (tid < GB * YY) {
        const int gg = tid >> 5, y = tid & 31;
        int cnt = s_count[gg];
        float inv = 1.0f / (cnt > 0 ? (float)cnt : 1.0f);
        float p = (float)s_cnt_sig[gg][y] * inv;
        s_feat[gg][y] = p;
        // safe entropy: 0*log(0) := 0 (matches grader-np; identical for p>0)
        float et = p > 0.0f ? -p * logf(p) : 0.0f;
        float t1 = p, t2 = -1e30f;
        #pragma unroll
        for (int off = 1; off < 32; off <<= 1) {
            float oe = __shfl_xor(et, off, 32);
            float o1 = __shfl_xor(t1, off, 32);
            float o2 = __shfl_xor(t2, off, 32);
            et += oe;
            float hi = fmaxf(t1, o1);
            float lo = fminf(t1, o1);
            t2 = fmaxf(lo, fmaxf(t2, o2));
            t1 = hi;
        }
        if (y == 0) {
            s_feat[gg][48] = et;
            s_feat[gg][49] = t1;
            s_feat[gg][50] = t2;
            s_feat[gg][51] = cnt > 0 ? inv : 0.0f;   // max(state_dist)
        }
    }
    if (tid < GB * VV) {
        const int gg = tid >> 4, v = tid & 15;
        s_feat[gg][YY + v] = (float)__popc(s_labmask[gg][v]);
    }
    __syncthreads();

    // ---- phase 3: h = gelu(feat @ W1 + b1), both slots in parallel ----
    {
        float acc = b1[lt];
        #pragma unroll
        for (int k = 0; k < 52; ++k) acc += s_feat[g][k] * W1[k * HID + lt];
        s_h[g][lt] = gelu_exact(acc);
    }
    __syncthreads();

    // ---- phase 4: z_logits = h @ W2 + b2 (chunked partials, round-10 order) ----
    {
        const int o = lt & 15, kc = lt >> 4;       // 32 chunks of 16
        float acc = 0.0f;
        #pragma unroll
        for (int q = 0; q < 16; ++q) {
            const int k = kc * 16 + q;
            acc += s_h[g][k] * W2[k * VV + o];
        }
        s_part[g][lt] = acc;
    }
    __syncthreads();
    if (tid < GB * VV) {
        const int gg = tid >> 4, o = tid & 15;
        float acc = b2[o];
        for (int kc = 0; kc < 32; ++kc) acc += s_part[gg][kc * 16 + o];
        s_logits[gg][o] = acc;
    }
    __syncthreads();

    // ---- phase 5: softmax + straight-through one-hot (one lane per slot) ----
    if (tid < GB) {
        const int gg = tid;
        float mx = s_logits[gg][0]; int am = 0;    // first-max tiebreak == np.argmax
        for (int o = 1; o < VV; ++o) if (s_logits[gg][o] > mx) { mx = s_logits[gg][o]; am = o; }
        float sum = 0.0f;
        float e[VV];
        #pragma unroll
        for (int o = 0; o < VV; ++o) { e[o] = expf(s_logits[gg][o] - mx); sum += e[o]; }
        float isum = 1.0f / sum;
        #pragma unroll
        for (int o = 0; o < VV; ++o) {
            float soft = e[o] * isum;
            s_fy[gg][YY + o] = ((o == am ? 1.0f : 0.0f) - soft) + soft;  // (hard - sg(soft)) + soft
        }
    }
    if (tid < GB * YY) {
        const int gg = tid >> 5, y = tid & 31;
        s_fy[gg][y] = s_feat[gg][y];
    }
    __syncthreads();

    // ---- phase 6: hy = gelu(fy @ Wy1 + by1) ----
    {
        float acc = by1[lt];
        #pragma unroll
        for (int k = 0; k < 48; ++k) acc += s_fy[g][k] * Wy1[k * HID + lt];
        s_h[g][lt] = gelu_exact(acc);
    }
    __syncthreads();

    // ---- phase 7: out = hy @ Wy2 + by2 ----
    {
        const int o = lt & 31, kc = lt >> 5;       // 16 chunks of 32
        float acc = 0.0f;
        #pragma unroll
        for (int q = 0; q < 32; ++q) {
            const int k = kc * 32 + q;
            acc += s_h[g][k] * Wy2[k * YY + o];
        }
        s_part[g][lt] = acc;
    }
    __syncthreads();
    if (tid < GB * YY) {
        const int gg = tid >> 5, o = tid & 31;
        float acc = by2[o];
        for (int kc = 0; kc < 16; ++kc) acc += s_part[gg][kc * 32 + o];
        out[(blockIdx.x * GB + gg) * YY + o] = acc;
    }
}

extern "C" void kernel_launch(void* const* d_in, const int* in_sizes, int n_in,
                              void* d_out, int out_size, void* d_ws, size_t ws_size,
                              hipStream_t stream) {
    // Size-based dispatch (unique sizes); {base_obs,b1,by1}=512 and
    // {actions,responses}=4096 resolved by dict order (verified rounds 8-10).
    const void *tables = nullptr, *sigma = nullptr, *tptr = nullptr;
    const void *W1 = nullptr, *W2 = nullptr, *Wy1 = nullptr, *Wy2 = nullptr;
    const void *b2 = nullptr, *by2 = nullptr;
    const void* amb512[3] = { nullptr, nullptr, nullptr }; int n512 = 0;
    const void* amb4096[2] = { nullptr, nullptr };         int n4096 = 0;

    for (int i = 0; i < n_in; ++i) {
        switch (in_sizes[i]) {
            case 67108864: tables = d_in[i]; break;           // 512*16*8192
            case 4194304:  sigma  = d_in[i]; break;           // 512*8192
            case 26624:    W1     = d_in[i]; break;           // 52*512
            case 8192:     W2     = d_in[i]; break;           // 512*16
            case 24576:    Wy1    = d_in[i]; break;           // 48*512
            case 16384:    Wy2    = d_in[i]; break;           // 512*32
            case 16:       b2     = d_in[i]; break;
            case 32:       by2    = d_in[i]; break;
            case 1:        tptr   = d_in[i]; break;
            case 4096:     if (n4096 < 2) amb4096[n4096++] = d_in[i]; break;
            case 512:      if (n512  < 3) amb512[n512++]   = d_in[i]; break;
            default: break;
        }
    }

    const void* base_obs  = amb512[0];
    const void* b1        = amb512[1];
    const void* by1       = amb512[2];
    const void* actions   = amb4096[0];
    const void* responses = amb4096[1];

    fused_model_kernel<<<NBLK, NTHR, 0, stream>>>(
        (const int*)tables, (const int*)sigma,
        (const int*)base_obs, (const int*)actions, (const int*)responses,
        (const unsigned*)tptr,
        (const float*)W1, (const float*)b1,
        (const float*)W2, (const float*)b2,
        (const float*)Wy1, (const float*)by1,
        (const float*)Wy2, (const float*)by2,
        (float*)d_out);
}